// Round 6
// baseline (204.620 us; speedup 1.0000x reference)
//
#include <hip/hip_runtime.h>
#include <cstddef>

#define LEN    1024
#define DIN    512
#define NHEAD  8
#define HDIM   64
#define BATCH  8

typedef __attribute__((ext_vector_type(8))) short  short8;
typedef __attribute__((ext_vector_type(4))) float  f32x4;

#define MFMA16(a, b, c) __builtin_amdgcn_mfma_f32_16x16x32_bf16((a), (b), (c), 0, 0, 0)
#define PERM_HI 0x07060302u
#define PERM_LO 0x05040100u

__device__ __forceinline__ unsigned short bf_hi(float x) {
    unsigned u = __float_as_uint(x);
    return (unsigned short)((u + 0x7fffu + ((u >> 16) & 1u)) >> 16);
}
__device__ __forceinline__ void bf_split(float x, unsigned short& h, unsigned short& l) {
    unsigned u  = __float_as_uint(x);
    unsigned hu = (u + 0x7fffu + ((u >> 16) & 1u)) >> 16;
    h = (unsigned short)hu;
    l = bf_hi(x - __uint_as_float(hu << 16));
}
__device__ __forceinline__ void unpack4(uint4 u, ushort4& h, ushort4& l) {
    h = make_ushort4((unsigned short)(u.x >> 16), (unsigned short)(u.y >> 16),
                     (unsigned short)(u.z >> 16), (unsigned short)(u.w >> 16));
    l = make_ushort4((unsigned short)(u.x & 0xffff), (unsigned short)(u.y & 0xffff),
                     (unsigned short)(u.z & 0xffff), (unsigned short)(u.w & 0xffff));
}
__device__ __forceinline__ void unpack8(uint4 a, uint4 b, uint4& h, uint4& l) {
    h = make_uint4(__builtin_amdgcn_perm(a.y, a.x, PERM_HI),
                   __builtin_amdgcn_perm(a.w, a.z, PERM_HI),
                   __builtin_amdgcn_perm(b.y, b.x, PERM_HI),
                   __builtin_amdgcn_perm(b.w, b.z, PERM_HI));
    l = make_uint4(__builtin_amdgcn_perm(a.y, a.x, PERM_LO),
                   __builtin_amdgcn_perm(a.w, a.z, PERM_LO),
                   __builtin_amdgcn_perm(b.y, b.x, PERM_LO),
                   __builtin_amdgcn_perm(b.w, b.z, PERM_LO));
}

// DPP cross-lane (16-lane row) reductions — full-rate VALU, no LDS.
template<int CTRL>
__device__ __forceinline__ float dpp_mov(float x) {
    return __int_as_float(__builtin_amdgcn_update_dpp(
        0, __float_as_int(x), CTRL, 0xF, 0xF, true));
}
__device__ __forceinline__ float red16_max(float x) {
    x = fmaxf(x, dpp_mov<0xB1>(x));
    x = fmaxf(x, dpp_mov<0x4E>(x));
    x = fmaxf(x, dpp_mov<0x141>(x));
    x = fmaxf(x, dpp_mov<0x140>(x));
    return x;
}
__device__ __forceinline__ float red16_sum(float x) {
    x += dpp_mov<0xB1>(x);
    x += dpp_mov<0x4E>(x);
    x += dpp_mov<0x141>(x);
    x += dpp_mov<0x140>(x);
    return x;
}

// ---------------------------------------------------------------------------
// wprep: W[512k][512n] fp32 -> Wt hi/lo bf16 in [n][k] layout (B-frag layout).
// ---------------------------------------------------------------------------
__global__ __launch_bounds__(256)
void wprep(const float* __restrict__ WQ, const float* __restrict__ WK,
           const float* __restrict__ WV, unsigned short* __restrict__ wt)
{
    __shared__ float T[64][68];
    const int z = blockIdx.z;
    const float* W = (z == 0) ? WQ : (z == 1) ? WK : WV;
    unsigned short* Wth = wt + (size_t)z * 524288;
    unsigned short* Wtl = Wth + 262144;
    const int k0 = blockIdx.x * 64, n0 = blockIdx.y * 64;
    const int t = threadIdx.x;
    #pragma unroll
    for (int e = 0; e < 4; ++e) {
        int f = e * 256 + t, r = f >> 4, c4 = (f & 15) << 2;
        *(float4*)&T[r][c4] = *(const float4*)&W[(size_t)(k0 + r) * 512 + n0 + c4];
    }
    __syncthreads();
    #pragma unroll
    for (int e = 0; e < 4; ++e) {
        int f = e * 256 + t, nr = f >> 4, kc4 = (f & 15) << 2;
        ushort4 h, l;
        bf_split(T[kc4 + 0][nr], h.x, l.x);
        bf_split(T[kc4 + 1][nr], h.y, l.y);
        bf_split(T[kc4 + 2][nr], h.z, l.z);
        bf_split(T[kc4 + 3][nr], h.w, l.w);
        *(ushort4*)&Wth[(size_t)(n0 + nr) * 512 + k0 + kc4] = h;
        *(ushort4*)&Wtl[(size_t)(n0 + nr) * 512 + k0 + kc4] = l;
    }
}

// ---------------------------------------------------------------------------
// proj_mfma (R5/R0 structure): C = X@W, split-bf16 MFMA. 128x128 tile, BK=32,
// inline fp32->hi/lo split of X. 3 blocks/CU.
// z<2 (q,k): 3-pass split; z=2 (v): 1-pass hi-only.
// Outputs: q,k packed (hi<<16|lo) uint [B,H,L,D]; v ushort [B,H,D,L].
// q pre-scaled by 0.125*log2(e).
// ---------------------------------------------------------------------------
#define PSTR 40   // LDS row stride in ushorts

__global__ __launch_bounds__(256, 3)
void proj_mfma(const float* __restrict__ Qin, const float* __restrict__ Kin,
               const float* __restrict__ Vin, const unsigned short* __restrict__ wt,
               unsigned int* __restrict__ qhl, unsigned int* __restrict__ khl,
               unsigned short* __restrict__ vh)
{
    __shared__ unsigned short Ah[128 * PSTR], Al[128 * PSTR],
                              Bh[128 * PSTR], Bl[128 * PSTR];
    const int z = blockIdx.z;
    const bool full = (z < 2);
    const float* X = (z == 0) ? Qin : (z == 1) ? Kin : Vin;
    const unsigned short* Wth = wt + (size_t)z * 524288;
    const unsigned short* Wtl = Wth + 262144;

    const int t = threadIdx.x, lane = t & 63, w = t >> 6;
    const int wm = w & 1, wn = w >> 1;
    const int m0 = blockIdx.x * 128, n0 = blockIdx.y * 128;
    const int lm = lane & 15, lq = lane >> 4;
    const int ar = t >> 1, ak = (t & 1) * 16;

    const float* Xp = X + (size_t)(m0 + ar) * 512 + ak;
    const unsigned short* Bph = Wth + (size_t)(n0 + ar) * 512 + ak;
    const unsigned short* Bpl = Wtl + (size_t)(n0 + ar) * 512 + ak;

    f32x4 acc[4][4];
    #pragma unroll
    for (int i = 0; i < 4; ++i)
        #pragma unroll
        for (int j = 0; j < 4; ++j) acc[i][j] = 0.f;

    // prefetch k0 = 0
    float4 av[4];
    uint4 bh0, bh1, bl0, bl1;
    #pragma unroll
    for (int e = 0; e < 4; ++e) av[e] = *(const float4*)(Xp + e * 4);
    bh0 = *(const uint4*)(Bph);
    bh1 = *(const uint4*)(Bph + 8);
    if (full) { bl0 = *(const uint4*)(Bpl); bl1 = *(const uint4*)(Bpl + 8); }

    for (int k0 = 0; k0 < 512; k0 += 32) {
        __syncthreads();                       // prev iter's frag reads done
        // ---- A: rounded-hi split, 16B conflict-free writes ----
        {
            const float* ff = (const float*)&av[0];   // av[4] is contiguous
            uint hw[16];
            #pragma unroll
            for (int i = 0; i < 16; ++i) hw[i] = __float_as_uint(ff[i]) & 0xffff0000u;
            uint4 ahv  = make_uint4(__builtin_amdgcn_perm(hw[1],  hw[0],  PERM_HI),
                                    __builtin_amdgcn_perm(hw[3],  hw[2],  PERM_HI),
                                    __builtin_amdgcn_perm(hw[5],  hw[4],  PERM_HI),
                                    __builtin_amdgcn_perm(hw[7],  hw[6],  PERM_HI));
            uint4 ahv2 = make_uint4(__builtin_amdgcn_perm(hw[9],  hw[8],  PERM_HI),
                                    __builtin_amdgcn_perm(hw[11], hw[10], PERM_HI),
                                    __builtin_amdgcn_perm(hw[13], hw[12], PERM_HI),
                                    __builtin_amdgcn_perm(hw[15], hw[14], PERM_HI));
            *(uint4*)&Ah[ar * PSTR + ak]     = ahv;
            *(uint4*)&Ah[ar * PSTR + ak + 8] = ahv2;
            if (full) {
                uint lo[8];
                #pragma unroll
                for (int i = 0; i < 8; ++i) {
                    float r0 = ff[2*i]   - __uint_as_float(hw[2*i]);
                    float r1 = ff[2*i+1] - __uint_as_float(hw[2*i+1]);
                    lo[i] = ((uint)bf_hi(r1) << 16) | bf_hi(r0);
                }
                *(uint4*)&Al[ar * PSTR + ak]     = make_uint4(lo[0], lo[1], lo[2], lo[3]);
                *(uint4*)&Al[ar * PSTR + ak + 8] = make_uint4(lo[4], lo[5], lo[6], lo[7]);
            }
        }
        // ---- B: straight copies ----
        *(uint4*)&Bh[ar * PSTR + ak]     = bh0;
        *(uint4*)&Bh[ar * PSTR + ak + 8] = bh1;
        if (full) {
            *(uint4*)&Bl[ar * PSTR + ak]     = bl0;
            *(uint4*)&Bl[ar * PSTR + ak + 8] = bl1;
        }
        __syncthreads();

        if (k0 + 32 < 512) {                   // prefetch next (overlaps MFMA)
            #pragma unroll
            for (int e = 0; e < 4; ++e) av[e] = *(const float4*)(Xp + k0 + 32 + e * 4);
            bh0 = *(const uint4*)(Bph + k0 + 32);
            bh1 = *(const uint4*)(Bph + k0 + 40);
            if (full) {
                bl0 = *(const uint4*)(Bpl + k0 + 32);
                bl1 = *(const uint4*)(Bpl + k0 + 40);
            }
        }

        short8 a_h[4], a_l[4];
        #pragma unroll
        for (int mi = 0; mi < 4; ++mi) {
            int off = (wm * 64 + mi * 16 + lm) * PSTR + lq * 8;
            a_h[mi] = *(const short8*)&Ah[off];
            if (full) a_l[mi] = *(const short8*)&Al[off];
        }
        #pragma unroll
        for (int ni = 0; ni < 4; ++ni) {
            int off = (wn * 64 + ni * 16 + lm) * PSTR + lq * 8;
            short8 b_h = *(const short8*)&Bh[off];
            if (full) {
                short8 b_l = *(const short8*)&Bl[off];
                #pragma unroll
                for (int mi = 0; mi < 4; ++mi) {
                    acc[mi][ni] = MFMA16(a_l[mi], b_h, acc[mi][ni]);
                    acc[mi][ni] = MFMA16(a_h[mi], b_l, acc[mi][ni]);
                    acc[mi][ni] = MFMA16(a_h[mi], b_h, acc[mi][ni]);
                }
            } else {
                #pragma unroll
                for (int mi = 0; mi < 4; ++mi)
                    acc[mi][ni] = MFMA16(a_h[mi], b_h, acc[mi][ni]);
            }
        }
    }

    if (z < 2) {
        unsigned int* o = (z == 0) ? qhl : khl;
        const float sc = (z == 0) ? 0.18033688011112042f : 1.0f;  // 0.125*log2(e)
        #pragma unroll
        for (int mi = 0; mi < 4; ++mi)
            #pragma unroll
            for (int ni = 0; ni < 4; ++ni) {
                int n_abs = n0 + wn * 64 + ni * 16 + lm;
                int hd = n_abs >> 6, d = n_abs & 63;
                #pragma unroll
                for (int r = 0; r < 4; ++r) {
                    int m_abs = m0 + wm * 64 + mi * 16 + lq * 4 + r;
                    int b = m_abs >> 10, li = m_abs & 1023;
                    unsigned short hv, lv;
                    bf_split(acc[mi][ni][r] * sc, hv, lv);
                    o[(((size_t)b * NHEAD + hd) * LEN + li) * HDIM + d] =
                        ((unsigned)hv << 16) | lv;
                }
            }
    } else {
        #pragma unroll
        for (int mi = 0; mi < 4; ++mi) {
            int m_base = m0 + wm * 64 + mi * 16 + lq * 4;
            int b = m_base >> 10, l0 = m_base & 1023;
            #pragma unroll
            for (int ni = 0; ni < 4; ++ni) {
                int n_abs = n0 + wn * 64 + ni * 16 + lm;
                int hd = n_abs >> 6, d = n_abs & 63;
                ushort4 hv = make_ushort4(bf_hi(acc[mi][ni][0]), bf_hi(acc[mi][ni][1]),
                                          bf_hi(acc[mi][ni][2]), bf_hi(acc[mi][ni][3]));
                *(ushort4*)&vh[(((size_t)b * NHEAD + hd) * HDIM + d) * LEN + l0] = hv;
            }
        }
    }
}

// ---------------------------------------------------------------------------
// attn_mfma R11 (= R10 resubmit; R10's bench was a container failure, not a
// kernel failure). KVBLK 64 -> 128: wall = straggler block's SEQUENTIAL iters
// (60us/16 iters ~ 9000 cyc/iter vs ~3000 throughput cyc -> ~6000 cyc/iter
// fixed barrier/latency cost). Halving iters (16->8) pays it half as often.
// R11 tweak vs R10: P-fragment reads moved inside the PV ks-loop (live pf =
// 8 VGPRs not 32) to keep peak VGPR below the 256 cliff.
// Causal: mask only at jb==qt; all waves active every iter.
// LDS 54,272 B -> 2 blocks/CU. Layout (ushort offsets):
//   Kh [0,9216) Kl [9216,18432)  128 rows x 72
//   Pb [0,16896) stride 132 (ALIASES Kh+Kl; B3 guards)
//   Vt [18432,27136)  64 d-rows x 136 (128 keys + pad)
//   Q overlay: Qsh [0,9216) Qsl [9216,18432)  (prologue only)
// Kept from R8/R9: qt map (XCD-local heads, balanced sums), no setprio.
// ---------------------------------------------------------------------------
__global__ __launch_bounds__(256)
void attn_mfma(const unsigned int* __restrict__ qhl, const unsigned int* __restrict__ khl,
               const unsigned short* __restrict__ vth, float* __restrict__ out)
{
    __shared__ __align__(16) unsigned short sm[27136];   // 54,272 B
    unsigned short* Kh  = sm;                     // 128*72
    unsigned short* Kl  = sm + 9216;              // 128*72
    unsigned short* Pb  = sm;                     // 128*132 = 16896 (ALIASES Kh+Kl)
    unsigned short* Vt  = sm + 18432;             // 64*136  [d][key]
    unsigned short* Qsh = sm;                     // staging overlay
    unsigned short* Qsl = sm + 9216;

    const int t = threadIdx.x, lane = t & 63, w = t >> 6;
    const int lm = lane & 15, lq = lane >> 4;
    const int bx = blockIdx.x;
    const int bh = bx & 63;
    const int g  = (bx >> 6) & 3;
    const int qt = (((bx >> 8) ^ bx) & 1) ? (7 - g) : g;
    const size_t base = (size_t)bh * LEN * HDIM;
    const unsigned int*   qb = qhl + base;
    const unsigned int*   kb = khl + base;
    const unsigned short* vb = vth + base;        // [d][l]
    const int Q0  = qt * 128;
    const int Q0w = Q0 + w * 32;

    // ---- stage Q (packed), pull split frags to registers ----
    #pragma unroll
    for (int e = 0; e < 8; ++e) {
        int f = e * 256 + t, r = f >> 4, c4 = (f & 15) << 2;
        uint4 u = *(const uint4*)&qb[(size_t)(Q0 + r) * 64 + c4];
        ushort4 h, l;
        unpack4(u, h, l);
        *(ushort4*)&Qsh[r * 72 + c4] = h;
        *(ushort4*)&Qsl[r * 72 + c4] = l;
    }
    __syncthreads();
    short8 qfh[2][2], qfl[2][2];
    #pragma unroll
    for (int mi = 0; mi < 2; ++mi)
        #pragma unroll
        for (int ks = 0; ks < 2; ++ks) {
            int off = (w * 32 + mi * 16 + lm) * 72 + ks * 32 + lq * 8;
            qfh[mi][ks] = *(const short8*)&Qsh[off];
            qfl[mi][ks] = *(const short8*)&Qsl[off];
        }

    float m_i[2][4], l_i[2][4];
    f32x4 oacc[2][4];
    #pragma unroll
    for (int mi = 0; mi < 2; ++mi)
        #pragma unroll
        for (int r = 0; r < 4; ++r) { m_i[mi][r] = -1e30f; l_i[mi][r] = 0.f; }
    #pragma unroll
    for (int mi = 0; mi < 2; ++mi)
        #pragma unroll
        for (int nd = 0; nd < 4; ++nd) oacc[mi][nd] = 0.f;

    // staging indices: K: row kr (0..127), half kq*32; V: d-row vd_, key seg vs16
    const int kr = t >> 1, kq = t & 1;
    const int vd_ = t >> 3, vs16 = (t & 7) << 4;

    // prefetch jb = 0
    uint4 kreg[8], vreg[4];
    #pragma unroll
    for (int e = 0; e < 8; ++e)
        kreg[e] = *(const uint4*)&kb[(size_t)kr * 64 + kq * 32 + e * 4];
    #pragma unroll
    for (int e = 0; e < 2; ++e)
        #pragma unroll
        for (int u = 0; u < 2; ++u)
            vreg[e * 2 + u] = *(const uint4*)&vb[(size_t)(e * 32 + vd_) * LEN + vs16 + u * 8];

    const int jend = qt;
    for (int jb = 0; jb <= jend; ++jb) {
        __syncthreads();   // B1: prev iter's P/V/frag reads done
        {
            uint4 h0, l0, h1, l1, h2, l2, h3, l3;
            unpack8(kreg[0], kreg[1], h0, l0);
            unpack8(kreg[2], kreg[3], h1, l1);
            unpack8(kreg[4], kreg[5], h2, l2);
            unpack8(kreg[6], kreg[7], h3, l3);
            int ko = kr * 72 + kq * 32;
            *(uint4*)&Kh[ko]      = h0;
            *(uint4*)&Kh[ko + 8]  = h1;
            *(uint4*)&Kh[ko + 16] = h2;
            *(uint4*)&Kh[ko + 24] = h3;
            *(uint4*)&Kl[ko]      = l0;
            *(uint4*)&Kl[ko + 8]  = l1;
            *(uint4*)&Kl[ko + 16] = l2;
            *(uint4*)&Kl[ko + 24] = l3;
            int vo = vd_ * 136 + vs16;
            *(uint4*)&Vt[vo]              = vreg[0];
            *(uint4*)&Vt[vo + 8]          = vreg[1];
            *(uint4*)&Vt[vo + 32 * 136]     = vreg[2];
            *(uint4*)&Vt[vo + 32 * 136 + 8] = vreg[3];
        }
        __syncthreads();   // B2: staging visible

        if (jb < jend) {   // prefetch next tile; overlaps all compute below
            #pragma unroll
            for (int e = 0; e < 8; ++e)
                kreg[e] = *(const uint4*)&kb[(size_t)((jb + 1) * 128 + kr) * 64 + kq * 32 + e * 4];
            #pragma unroll
            for (int e = 0; e < 2; ++e)
                #pragma unroll
                for (int u = 0; u < 2; ++u)
                    vreg[e * 2 + u] = *(const uint4*)&vb[(size_t)(e * 32 + vd_) * LEN + (jb + 1) * 128 + vs16 + u * 8];
        }

        f32x4 sf[2][8];
        #pragma unroll
        for (int mi = 0; mi < 2; ++mi)
            #pragma unroll
            for (int ni = 0; ni < 8; ++ni) sf[mi][ni] = 0.f;
        #pragma unroll
        for (int ks = 0; ks < 2; ++ks)
            #pragma unroll
            for (int ni = 0; ni < 8; ++ni) {
                int off = (ni * 16 + lm) * 72 + ks * 32 + lq * 8;
                short8 b_h = *(const short8*)&Kh[off];
                short8 b_l = *(const short8*)&Kl[off];
                #pragma unroll
                for (int mi = 0; mi < 2; ++mi) {
                    sf[mi][ni] = MFMA16(qfl[mi][ks], b_h, sf[mi][ni]);
                    sf[mi][ni] = MFMA16(qfh[mi][ks], b_l, sf[mi][ni]);
                    sf[mi][ni] = MFMA16(qfh[mi][ks], b_h, sf[mi][ni]);
                }
            }
        if (jb == jend) {   // causal mask: only the diagonal tile
            #pragma unroll
            for (int mi = 0; mi < 2; ++mi)
                #pragma unroll
                for (int ni = 0; ni < 8; ++ni) {
                    int key = jb * 128 + ni * 16 + lm;
                    #pragma unroll
                    for (int r = 0; r < 4; ++r) {
                        int qi = Q0w + mi * 16 + lq * 4 + r;
                        if (key > qi) sf[mi][ni][r] = -1e30f;
                    }
                }
        }
        __syncthreads();   // B3: all K reads done — P may overwrite K region

        // online softmax (base 2); rows on 16-lane groups -> DPP reduce
        #pragma unroll
        for (int mi = 0; mi < 2; ++mi)
            #pragma unroll
            for (int r = 0; r < 4; ++r) {
                float mv = fmaxf(fmaxf(fmaxf(sf[mi][0][r], sf[mi][1][r]),
                                       fmaxf(sf[mi][2][r], sf[mi][3][r])),
                                 fmaxf(fmaxf(sf[mi][4][r], sf[mi][5][r]),
                                       fmaxf(sf[mi][6][r], sf[mi][7][r])));
                mv = red16_max(mv);
                float mo = m_i[mi][r];
                float mn = fmaxf(mo, mv);
                float al = __builtin_amdgcn_exp2f(mo - mn);
                m_i[mi][r] = mn;
                float rs = 0.f;
                int prow = (w * 32 + mi * 16 + lq * 4 + r) * 132 + lm;
                #pragma unroll
                for (int ni = 0; ni < 8; ++ni) {
                    float p = __builtin_amdgcn_exp2f(sf[mi][ni][r] - mn);
                    rs += p;
                    Pb[prow + ni * 16] = bf_hi(p);
                }
                rs = red16_sum(rs);
                l_i[mi][r] = l_i[mi][r] * al + rs;
                #pragma unroll
                for (int nd = 0; nd < 4; ++nd) oacc[mi][nd][r] *= al;
            }
        // P round-trip: same-wave rows, lgkmcnt ordering suffices.
        // pf read per-ks (8 live VGPRs, not 32) to stay under the 256 cliff.
        #pragma unroll
        for (int ks = 0; ks < 4; ++ks) {
            short8 pf0 = *(const short8*)&Pb[(w * 32 + 0  + lm) * 132 + ks * 32 + lq * 8];
            short8 pf1 = *(const short8*)&Pb[(w * 32 + 16 + lm) * 132 + ks * 32 + lq * 8];
            #pragma unroll
            for (int nd = 0; nd < 4; ++nd) {
                short8 vf = *(const short8*)&Vt[(nd * 16 + lm) * 136 + ks * 32 + lq * 8];
                oacc[0][nd] = MFMA16(pf0, vf, oacc[0][nd]);
                oacc[1][nd] = MFMA16(pf1, vf, oacc[1][nd]);
            }
        }
    }

    // epilogue: divide by l, write [B, L, H*D] fp32
    const int b = bh >> 3, hd = bh & 7;
    #pragma unroll
    for (int mi = 0; mi < 2; ++mi)
        #pragma unroll
        for (int r = 0; r < 4; ++r) {
            int qrow = Q0w + mi * 16 + lq * 4 + r;
            float inv = 1.0f / l_i[mi][r];
            #pragma unroll
            for (int nd = 0; nd < 4; ++nd) {
                int d = nd * 16 + lm;
                out[((size_t)b * LEN + qrow) * (NHEAD * HDIM) + hd * 64 + d] =
                    oacc[mi][nd][r] * inv;
            }
        }
}

// ---------------------------------------------------------------------------
extern "C" void kernel_launch(void* const* d_in, const int* in_sizes, int n_in,
                              void* d_out, int out_size, void* d_ws, size_t ws_size,
                              hipStream_t stream)
{
    const float* Qin = (const float*)d_in[0];
    const float* Kin = (const float*)d_in[1];
    const float* Vin = (const float*)d_in[2];
    const float* WQ  = (const float*)d_in[3];
    const float* WK  = (const float*)d_in[4];
    const float* WV  = (const float*)d_in[5];

    const size_t per = (size_t)BATCH * NHEAD * LEN * HDIM;   // 4,194,304 elements
    unsigned int*   qhl = (unsigned int*)d_ws;               // 16 MB
    unsigned int*   khl = qhl + per;                         // 16 MB
    unsigned short* vh  = (unsigned short*)(khl + per);      // 8 MB
    unsigned short* wt  = vh + per;                          // 3 MB   (total 43 MB)

    wprep    <<<dim3(8, 8, 3),  256, 0, stream>>>(WQ, WK, WV, wt);
    proj_mfma<<<dim3(64, 4, 3), 256, 0, stream>>>(Qin, Kin, Vin, wt, qhl, khl, vh);
    attn_mfma<<<dim3(512),      256, 0, stream>>>(qhl, khl, vh, (float*)d_out);
}

// Round 7
// 186.275 us; speedup vs baseline: 1.0985x; 1.0985x over previous
//
#include <hip/hip_runtime.h>
#include <cstddef>

#define LEN    1024
#define DIN    512
#define NHEAD  8
#define HDIM   64
#define BATCH  8

typedef __attribute__((ext_vector_type(8))) short  short8;
typedef __attribute__((ext_vector_type(4))) float  f32x4;

#define MFMA16(a, b, c) __builtin_amdgcn_mfma_f32_16x16x32_bf16((a), (b), (c), 0, 0, 0)
#define PERM_HI 0x07060302u
#define PERM_LO 0x05040100u

__device__ __forceinline__ unsigned short bf_hi(float x) {
    unsigned u = __float_as_uint(x);
    return (unsigned short)((u + 0x7fffu + ((u >> 16) & 1u)) >> 16);
}
__device__ __forceinline__ void bf_split(float x, unsigned short& h, unsigned short& l) {
    unsigned u  = __float_as_uint(x);
    unsigned hu = (u + 0x7fffu + ((u >> 16) & 1u)) >> 16;
    h = (unsigned short)hu;
    l = bf_hi(x - __uint_as_float(hu << 16));
}
__device__ __forceinline__ void unpack4(uint4 u, ushort4& h, ushort4& l) {
    h = make_ushort4((unsigned short)(u.x >> 16), (unsigned short)(u.y >> 16),
                     (unsigned short)(u.z >> 16), (unsigned short)(u.w >> 16));
    l = make_ushort4((unsigned short)(u.x & 0xffff), (unsigned short)(u.y & 0xffff),
                     (unsigned short)(u.z & 0xffff), (unsigned short)(u.w & 0xffff));
}
__device__ __forceinline__ void unpack8(uint4 a, uint4 b, uint4& h, uint4& l) {
    h = make_uint4(__builtin_amdgcn_perm(a.y, a.x, PERM_HI),
                   __builtin_amdgcn_perm(a.w, a.z, PERM_HI),
                   __builtin_amdgcn_perm(b.y, b.x, PERM_HI),
                   __builtin_amdgcn_perm(b.w, b.z, PERM_HI));
    l = make_uint4(__builtin_amdgcn_perm(a.y, a.x, PERM_LO),
                   __builtin_amdgcn_perm(a.w, a.z, PERM_LO),
                   __builtin_amdgcn_perm(b.y, b.x, PERM_LO),
                   __builtin_amdgcn_perm(b.w, b.z, PERM_LO));
}

// DPP cross-lane (16-lane row) reductions — full-rate VALU, no LDS.
template<int CTRL>
__device__ __forceinline__ float dpp_mov(float x) {
    return __int_as_float(__builtin_amdgcn_update_dpp(
        0, __float_as_int(x), CTRL, 0xF, 0xF, true));
}
__device__ __forceinline__ float red16_max(float x) {
    x = fmaxf(x, dpp_mov<0xB1>(x));
    x = fmaxf(x, dpp_mov<0x4E>(x));
    x = fmaxf(x, dpp_mov<0x141>(x));
    x = fmaxf(x, dpp_mov<0x140>(x));
    return x;
}
__device__ __forceinline__ float red16_sum(float x) {
    x += dpp_mov<0xB1>(x);
    x += dpp_mov<0x4E>(x);
    x += dpp_mov<0x141>(x);
    x += dpp_mov<0x140>(x);
    return x;
}

// ---------------------------------------------------------------------------
// wprep: W[512k][512n] fp32 -> Wt hi/lo bf16 in [n][k] layout (B-frag layout).
// ---------------------------------------------------------------------------
__global__ __launch_bounds__(256)
void wprep(const float* __restrict__ WQ, const float* __restrict__ WK,
           const float* __restrict__ WV, unsigned short* __restrict__ wt)
{
    __shared__ float T[64][68];
    const int z = blockIdx.z;
    const float* W = (z == 0) ? WQ : (z == 1) ? WK : WV;
    unsigned short* Wth = wt + (size_t)z * 524288;
    unsigned short* Wtl = Wth + 262144;
    const int k0 = blockIdx.x * 64, n0 = blockIdx.y * 64;
    const int t = threadIdx.x;
    #pragma unroll
    for (int e = 0; e < 4; ++e) {
        int f = e * 256 + t, r = f >> 4, c4 = (f & 15) << 2;
        *(float4*)&T[r][c4] = *(const float4*)&W[(size_t)(k0 + r) * 512 + n0 + c4];
    }
    __syncthreads();
    #pragma unroll
    for (int e = 0; e < 4; ++e) {
        int f = e * 256 + t, nr = f >> 4, kc4 = (f & 15) << 2;
        ushort4 h, l;
        bf_split(T[kc4 + 0][nr], h.x, l.x);
        bf_split(T[kc4 + 1][nr], h.y, l.y);
        bf_split(T[kc4 + 2][nr], h.z, l.z);
        bf_split(T[kc4 + 3][nr], h.w, l.w);
        *(ushort4*)&Wth[(size_t)(n0 + nr) * 512 + k0 + kc4] = h;
        *(ushort4*)&Wtl[(size_t)(n0 + nr) * 512 + k0 + kc4] = l;
    }
}

// ---------------------------------------------------------------------------
// proj_mfma (R5/R0 structure): C = X@W, split-bf16 MFMA. 128x128 tile, BK=32,
// inline fp32->hi/lo split of X. 3 blocks/CU.
// z<2 (q,k): 3-pass split; z=2 (v): 1-pass hi-only.
// Outputs: q,k packed (hi<<16|lo) uint [B,H,L,D]; v ushort [B,H,D,L].
// q pre-scaled by 0.125*log2(e).
// ---------------------------------------------------------------------------
#define PSTR 40   // LDS row stride in ushorts

__global__ __launch_bounds__(256, 3)
void proj_mfma(const float* __restrict__ Qin, const float* __restrict__ Kin,
               const float* __restrict__ Vin, const unsigned short* __restrict__ wt,
               unsigned int* __restrict__ qhl, unsigned int* __restrict__ khl,
               unsigned short* __restrict__ vh)
{
    __shared__ unsigned short Ah[128 * PSTR], Al[128 * PSTR],
                              Bh[128 * PSTR], Bl[128 * PSTR];
    const int z = blockIdx.z;
    const bool full = (z < 2);
    const float* X = (z == 0) ? Qin : (z == 1) ? Kin : Vin;
    const unsigned short* Wth = wt + (size_t)z * 524288;
    const unsigned short* Wtl = Wth + 262144;

    const int t = threadIdx.x, lane = t & 63, w = t >> 6;
    const int wm = w & 1, wn = w >> 1;
    const int m0 = blockIdx.x * 128, n0 = blockIdx.y * 128;
    const int lm = lane & 15, lq = lane >> 4;
    const int ar = t >> 1, ak = (t & 1) * 16;

    const float* Xp = X + (size_t)(m0 + ar) * 512 + ak;
    const unsigned short* Bph = Wth + (size_t)(n0 + ar) * 512 + ak;
    const unsigned short* Bpl = Wtl + (size_t)(n0 + ar) * 512 + ak;

    f32x4 acc[4][4];
    #pragma unroll
    for (int i = 0; i < 4; ++i)
        #pragma unroll
        for (int j = 0; j < 4; ++j) acc[i][j] = 0.f;

    // prefetch k0 = 0
    float4 av[4];
    uint4 bh0, bh1, bl0, bl1;
    #pragma unroll
    for (int e = 0; e < 4; ++e) av[e] = *(const float4*)(Xp + e * 4);
    bh0 = *(const uint4*)(Bph);
    bh1 = *(const uint4*)(Bph + 8);
    if (full) { bl0 = *(const uint4*)(Bpl); bl1 = *(const uint4*)(Bpl + 8); }

    for (int k0 = 0; k0 < 512; k0 += 32) {
        __syncthreads();                       // prev iter's frag reads done
        // ---- A: rounded-hi split, 16B conflict-free writes ----
        {
            const float* ff = (const float*)&av[0];   // av[4] is contiguous
            uint hw[16];
            #pragma unroll
            for (int i = 0; i < 16; ++i) hw[i] = __float_as_uint(ff[i]) & 0xffff0000u;
            uint4 ahv  = make_uint4(__builtin_amdgcn_perm(hw[1],  hw[0],  PERM_HI),
                                    __builtin_amdgcn_perm(hw[3],  hw[2],  PERM_HI),
                                    __builtin_amdgcn_perm(hw[5],  hw[4],  PERM_HI),
                                    __builtin_amdgcn_perm(hw[7],  hw[6],  PERM_HI));
            uint4 ahv2 = make_uint4(__builtin_amdgcn_perm(hw[9],  hw[8],  PERM_HI),
                                    __builtin_amdgcn_perm(hw[11], hw[10], PERM_HI),
                                    __builtin_amdgcn_perm(hw[13], hw[12], PERM_HI),
                                    __builtin_amdgcn_perm(hw[15], hw[14], PERM_HI));
            *(uint4*)&Ah[ar * PSTR + ak]     = ahv;
            *(uint4*)&Ah[ar * PSTR + ak + 8] = ahv2;
            if (full) {
                uint lo[8];
                #pragma unroll
                for (int i = 0; i < 8; ++i) {
                    float r0 = ff[2*i]   - __uint_as_float(hw[2*i]);
                    float r1 = ff[2*i+1] - __uint_as_float(hw[2*i+1]);
                    lo[i] = ((uint)bf_hi(r1) << 16) | bf_hi(r0);
                }
                *(uint4*)&Al[ar * PSTR + ak]     = make_uint4(lo[0], lo[1], lo[2], lo[3]);
                *(uint4*)&Al[ar * PSTR + ak + 8] = make_uint4(lo[4], lo[5], lo[6], lo[7]);
            }
        }
        // ---- B: straight copies ----
        *(uint4*)&Bh[ar * PSTR + ak]     = bh0;
        *(uint4*)&Bh[ar * PSTR + ak + 8] = bh1;
        if (full) {
            *(uint4*)&Bl[ar * PSTR + ak]     = bl0;
            *(uint4*)&Bl[ar * PSTR + ak + 8] = bl1;
        }
        __syncthreads();

        if (k0 + 32 < 512) {                   // prefetch next (overlaps MFMA)
            #pragma unroll
            for (int e = 0; e < 4; ++e) av[e] = *(const float4*)(Xp + k0 + 32 + e * 4);
            bh0 = *(const uint4*)(Bph + k0 + 32);
            bh1 = *(const uint4*)(Bph + k0 + 40);
            if (full) {
                bl0 = *(const uint4*)(Bpl + k0 + 32);
                bl1 = *(const uint4*)(Bpl + k0 + 40);
            }
        }

        short8 a_h[4], a_l[4];
        #pragma unroll
        for (int mi = 0; mi < 4; ++mi) {
            int off = (wm * 64 + mi * 16 + lm) * PSTR + lq * 8;
            a_h[mi] = *(const short8*)&Ah[off];
            if (full) a_l[mi] = *(const short8*)&Al[off];
        }
        #pragma unroll
        for (int ni = 0; ni < 4; ++ni) {
            int off = (wn * 64 + ni * 16 + lm) * PSTR + lq * 8;
            short8 b_h = *(const short8*)&Bh[off];
            if (full) {
                short8 b_l = *(const short8*)&Bl[off];
                #pragma unroll
                for (int mi = 0; mi < 4; ++mi) {
                    acc[mi][ni] = MFMA16(a_l[mi], b_h, acc[mi][ni]);
                    acc[mi][ni] = MFMA16(a_h[mi], b_l, acc[mi][ni]);
                    acc[mi][ni] = MFMA16(a_h[mi], b_h, acc[mi][ni]);
                }
            } else {
                #pragma unroll
                for (int mi = 0; mi < 4; ++mi)
                    acc[mi][ni] = MFMA16(a_h[mi], b_h, acc[mi][ni]);
            }
        }
    }

    if (z < 2) {
        unsigned int* o = (z == 0) ? qhl : khl;
        const float sc = (z == 0) ? 0.18033688011112042f : 1.0f;  // 0.125*log2(e)
        #pragma unroll
        for (int mi = 0; mi < 4; ++mi)
            #pragma unroll
            for (int ni = 0; ni < 4; ++ni) {
                int n_abs = n0 + wn * 64 + ni * 16 + lm;
                int hd = n_abs >> 6, d = n_abs & 63;
                #pragma unroll
                for (int r = 0; r < 4; ++r) {
                    int m_abs = m0 + wm * 64 + mi * 16 + lq * 4 + r;
                    int b = m_abs >> 10, li = m_abs & 1023;
                    unsigned short hv, lv;
                    bf_split(acc[mi][ni][r] * sc, hv, lv);
                    o[(((size_t)b * NHEAD + hd) * LEN + li) * HDIM + d] =
                        ((unsigned)hv << 16) | lv;
                }
            }
    } else {
        #pragma unroll
        for (int mi = 0; mi < 4; ++mi) {
            int m_base = m0 + wm * 64 + mi * 16 + lq * 4;
            int b = m_base >> 10, l0 = m_base & 1023;
            #pragma unroll
            for (int ni = 0; ni < 4; ++ni) {
                int n_abs = n0 + wn * 64 + ni * 16 + lm;
                int hd = n_abs >> 6, d = n_abs & 63;
                ushort4 hv = make_ushort4(bf_hi(acc[mi][ni][0]), bf_hi(acc[mi][ni][1]),
                                          bf_hi(acc[mi][ni][2]), bf_hi(acc[mi][ni][3]));
                *(ushort4*)&vh[(((size_t)b * NHEAD + hd) * HDIM + d) * LEN + l0] = hv;
            }
        }
    }
}

// ---------------------------------------------------------------------------
// attn_mfma R12: back to KVBLK=64 (R11's 128 regressed 60->92: VGPR ceiling,
// compiler spill, WRITE_SIZE +7MB scratch). Two changes vs R9:
//  (1) Pb UN-ALIASED from Kh/Kl (own region at 13824) -> B3 DELETED.
//      P writes are wave-private (each wave writes only its 32 rows) and
//      QK's K-reads need no fence against them; next iter's B1 still guards
//      the K/V overwrite. 2 barriers/iter instead of 3.
//      LDS 36,864 -> 47,104 B: still 2 blocks/CU (grid 512 = 2/CU exactly).
//  (2) K hi/lo unpack hoisted out of the B1->B2 staging window: unpack runs
//      at end of loop body on the prefetched kreg (waves drifted there);
//      staging phase is pure ds_write_b128.
// Kept from R9: KVBLK=64, qt map (XCD-local heads), P stride 76, no setprio.
// LDS layout (ushort offsets): Kh [0,4608) Kl [4608,9216) Vt [9216,13824)
//   Pb [13824,23552) stride 76; Q overlay Qsh [0,9216) Qsl [9216,18432)
//   (prologue only; first staging writes happen after B1).
// ---------------------------------------------------------------------------
__global__ __launch_bounds__(256)
void attn_mfma(const unsigned int* __restrict__ qhl, const unsigned int* __restrict__ khl,
               const unsigned short* __restrict__ vth, float* __restrict__ out)
{
    __shared__ __align__(16) unsigned short sm[23552];   // 47,104 B
    unsigned short* Kh  = sm;                     // 64*72 = 4608
    unsigned short* Kl  = sm + 4608;              // 64*72
    unsigned short* Vt  = sm + 9216;              // 64*72  [d][key]
    unsigned short* Pb  = sm + 13824;             // 128*76 = 9728 (own region)
    unsigned short* Qsh = sm;                     // staging overlay (prologue)
    unsigned short* Qsl = sm + 9216;

    const int t = threadIdx.x, lane = t & 63, w = t >> 6;
    const int lm = lane & 15, lq = lane >> 4;
    const int bx = blockIdx.x;
    const int bh = bx & 63;
    const int g  = (bx >> 6) & 3;
    const int qt = (((bx >> 8) ^ bx) & 1) ? (7 - g) : g;
    const size_t base = (size_t)bh * LEN * HDIM;
    const unsigned int*   qb = qhl + base;
    const unsigned int*   kb = khl + base;
    const unsigned short* vb = vth + base;        // [d][l]
    const int Q0  = qt * 128;
    const int Q0w = Q0 + w * 32;

    // staging indices: K: row kr (0..63), d-quarter kq*16; V: d-row vd_, key seg vs8
    const int kr = t >> 2, kq = t & 3;
    const int vd_ = t >> 3, vs8 = (t & 7) << 3;

    // prefetch tile jb=0 and pre-unpack K to hi/lo regs (overlaps Q prologue)
    uint4 kreg[4], vreg[2];
    uint4 kh0, kh1, kl0, kl1;
    #pragma unroll
    for (int e = 0; e < 4; ++e)
        kreg[e] = *(const uint4*)&kb[(size_t)kr * 64 + kq * 16 + e * 4];
    #pragma unroll
    for (int e = 0; e < 2; ++e)
        vreg[e] = *(const uint4*)&vb[(size_t)(e * 32 + vd_) * LEN + vs8];

    // ---- stage Q (packed), pull split frags to registers ----
    #pragma unroll
    for (int e = 0; e < 8; ++e) {
        int f = e * 256 + t, r = f >> 4, c4 = (f & 15) << 2;
        uint4 u = *(const uint4*)&qb[(size_t)(Q0 + r) * 64 + c4];
        ushort4 h, l;
        unpack4(u, h, l);
        *(ushort4*)&Qsh[r * 72 + c4] = h;
        *(ushort4*)&Qsl[r * 72 + c4] = l;
    }
    unpack8(kreg[0], kreg[1], kh0, kl0);
    unpack8(kreg[2], kreg[3], kh1, kl1);
    __syncthreads();
    short8 qfh[2][2], qfl[2][2];
    #pragma unroll
    for (int mi = 0; mi < 2; ++mi)
        #pragma unroll
        for (int ks = 0; ks < 2; ++ks) {
            int off = (w * 32 + mi * 16 + lm) * 72 + ks * 32 + lq * 8;
            qfh[mi][ks] = *(const short8*)&Qsh[off];
            qfl[mi][ks] = *(const short8*)&Qsl[off];
        }

    float m_i[2][4], l_i[2][4];
    f32x4 oacc[2][4];
    #pragma unroll
    for (int mi = 0; mi < 2; ++mi)
        #pragma unroll
        for (int r = 0; r < 4; ++r) { m_i[mi][r] = -1e30f; l_i[mi][r] = 0.f; }
    #pragma unroll
    for (int mi = 0; mi < 2; ++mi)
        #pragma unroll
        for (int nd = 0; nd < 4; ++nd) oacc[mi][nd] = 0.f;

    const int jend = 2 * qt + 1;
    for (int jb = 0; jb <= jend; ++jb) {
        __syncthreads();   // B1: prev iter's K/V frag reads done (also guards Q overlay)
        {
            int ko = kr * 72 + kq * 16;
            *(uint4*)&Kh[ko]     = kh0;
            *(uint4*)&Kh[ko + 8] = kh1;
            *(uint4*)&Kl[ko]     = kl0;
            *(uint4*)&Kl[ko + 8] = kl1;
            *(uint4*)&Vt[(vd_)      * 72 + vs8] = vreg[0];
            *(uint4*)&Vt[(vd_ + 32) * 72 + vs8] = vreg[1];
        }
        __syncthreads();   // B2: staging visible

        if (jb < jend) {   // prefetch next tile; overlaps all compute below
            #pragma unroll
            for (int e = 0; e < 4; ++e)
                kreg[e] = *(const uint4*)&kb[(size_t)((jb + 1) * 64 + kr) * 64 + kq * 16 + e * 4];
            #pragma unroll
            for (int e = 0; e < 2; ++e)
                vreg[e] = *(const uint4*)&vb[(size_t)(e * 32 + vd_) * LEN + (jb + 1) * 64 + vs8];
        }

        const bool active = (jb * 64 <= Q0w + 31);
        if (active) {
            f32x4 sf[2][4];
            #pragma unroll
            for (int mi = 0; mi < 2; ++mi)
                #pragma unroll
                for (int ni = 0; ni < 4; ++ni) sf[mi][ni] = 0.f;
            #pragma unroll
            for (int ks = 0; ks < 2; ++ks)
                #pragma unroll
                for (int ni = 0; ni < 4; ++ni) {
                    int off = (ni * 16 + lm) * 72 + ks * 32 + lq * 8;
                    short8 b_h = *(const short8*)&Kh[off];
                    short8 b_l = *(const short8*)&Kl[off];
                    #pragma unroll
                    for (int mi = 0; mi < 2; ++mi) {
                        sf[mi][ni] = MFMA16(qfl[mi][ks], b_h, sf[mi][ni]);
                        sf[mi][ni] = MFMA16(qfh[mi][ks], b_l, sf[mi][ni]);
                        sf[mi][ni] = MFMA16(qfh[mi][ks], b_h, sf[mi][ni]);
                    }
                }
            if (jb * 64 + 63 > Q0w) {   // causal mask near diagonal
                #pragma unroll
                for (int mi = 0; mi < 2; ++mi)
                    #pragma unroll
                    for (int ni = 0; ni < 4; ++ni) {
                        int key = jb * 64 + ni * 16 + lm;
                        #pragma unroll
                        for (int r = 0; r < 4; ++r) {
                            int qi = Q0w + mi * 16 + lq * 4 + r;
                            if (key > qi) sf[mi][ni][r] = -1e30f;
                        }
                    }
            }

            // online softmax (base 2); P region is wave-private -> NO barrier
            #pragma unroll
            for (int mi = 0; mi < 2; ++mi)
                #pragma unroll
                for (int r = 0; r < 4; ++r) {
                    float mv = fmaxf(fmaxf(sf[mi][0][r], sf[mi][1][r]),
                                     fmaxf(sf[mi][2][r], sf[mi][3][r]));
                    mv = red16_max(mv);
                    float mo = m_i[mi][r];
                    float mn = fmaxf(mo, mv);
                    float al = __builtin_amdgcn_exp2f(mo - mn);
                    m_i[mi][r] = mn;
                    float rs = 0.f;
                    int prow = (w * 32 + mi * 16 + lq * 4 + r) * 76 + lm;
                    #pragma unroll
                    for (int ni = 0; ni < 4; ++ni) {
                        float p = __builtin_amdgcn_exp2f(sf[mi][ni][r] - mn);
                        rs += p;
                        Pb[prow + ni * 16] = bf_hi(p);
                    }
                    rs = red16_sum(rs);
                    l_i[mi][r] = l_i[mi][r] * al + rs;
                    #pragma unroll
                    for (int nd = 0; nd < 4; ++nd) oacc[mi][nd][r] *= al;
                }
            // P round-trip: same-wave rows, lgkmcnt ordering suffices
            short8 pf[2][2];
            #pragma unroll
            for (int mi = 0; mi < 2; ++mi)
                #pragma unroll
                for (int ks = 0; ks < 2; ++ks)
                    pf[mi][ks] = *(const short8*)&Pb[(w * 32 + mi * 16 + lm) * 76 + ks * 32 + lq * 8];
            #pragma unroll
            for (int ks = 0; ks < 2; ++ks)
                #pragma unroll
                for (int nd = 0; nd < 4; ++nd) {
                    short8 vf = *(const short8*)&Vt[(nd * 16 + lm) * 72 + ks * 32 + lq * 8];
                    #pragma unroll
                    for (int mi = 0; mi < 2; ++mi)
                        oacc[mi][nd] = MFMA16(pf[mi][ks], vf, oacc[mi][nd]);
                }
        }

        if (jb < jend) {   // unpack next K tile OUTSIDE the staging window
            unpack8(kreg[0], kreg[1], kh0, kl0);
            unpack8(kreg[2], kreg[3], kh1, kl1);
        }
    }

    // epilogue: divide by l, write [B, L, H*D] fp32
    const int b = bh >> 3, hd = bh & 7;
    #pragma unroll
    for (int mi = 0; mi < 2; ++mi)
        #pragma unroll
        for (int r = 0; r < 4; ++r) {
            int qrow = Q0w + mi * 16 + lq * 4 + r;
            float inv = 1.0f / l_i[mi][r];
            #pragma unroll
            for (int nd = 0; nd < 4; ++nd) {
                int d = nd * 16 + lm;
                out[((size_t)b * LEN + qrow) * (NHEAD * HDIM) + hd * 64 + d] =
                    oacc[mi][nd][r] * inv;
            }
        }
}

// ---------------------------------------------------------------------------
extern "C" void kernel_launch(void* const* d_in, const int* in_sizes, int n_in,
                              void* d_out, int out_size, void* d_ws, size_t ws_size,
                              hipStream_t stream)
{
    const float* Qin = (const float*)d_in[0];
    const float* Kin = (const float*)d_in[1];
    const float* Vin = (const float*)d_in[2];
    const float* WQ  = (const float*)d_in[3];
    const float* WK  = (const float*)d_in[4];
    const float* WV  = (const float*)d_in[5];

    const size_t per = (size_t)BATCH * NHEAD * LEN * HDIM;   // 4,194,304 elements
    unsigned int*   qhl = (unsigned int*)d_ws;               // 16 MB
    unsigned int*   khl = qhl + per;                         // 16 MB
    unsigned short* vh  = (unsigned short*)(khl + per);      // 8 MB
    unsigned short* wt  = vh + per;                          // 3 MB   (total 43 MB)

    wprep    <<<dim3(8, 8, 3),  256, 0, stream>>>(WQ, WK, WV, wt);
    proj_mfma<<<dim3(64, 4, 3), 256, 0, stream>>>(Qin, Kin, Vin, wt, qhl, khl, vh);
    attn_mfma<<<dim3(512),      256, 0, stream>>>(qhl, khl, vh, (float*)d_out);
}